// Round 4
// baseline (1885.076 us; speedup 1.0000x reference)
//
#include <hip/hip_runtime.h>

#define BB 32
#define SS 128
#define LL 4096
#define KK 129
#define NST 10

// ---------- constexpr twiddles: TW[j] = e^{-2*pi*i*j/128}, j in [0,64) ----------
constexpr double PI_D = 3.141592653589793238462643383279502884;
constexpr double red_sin(double x){ // |x| <= pi/2, Taylor to x^17
  double x2 = x*x, t = x, r = x;
  t *= -x2/6.0;   r += t;
  t *= -x2/20.0;  r += t;
  t *= -x2/42.0;  r += t;
  t *= -x2/72.0;  r += t;
  t *= -x2/110.0; r += t;
  t *= -x2/156.0; r += t;
  t *= -x2/210.0; r += t;
  t *= -x2/272.0; r += t;
  return r;
}
constexpr double csin_d(double x){
  while (x >  PI_D) x -= 2.0*PI_D;
  while (x < -PI_D) x += 2.0*PI_D;
  if (x >  PI_D*0.5)      x =  PI_D - x;
  else if (x < -PI_D*0.5) x = -PI_D - x;
  return red_sin(x);
}
constexpr double ccos_d(double x){ return csin_d(x + PI_D*0.5); }
struct TWT { float c[64]; float s[64]; };
constexpr TWT make_tw(){
  TWT t{};
  for (int j = 0; j < 64; j++){
    double a = -2.0*PI_D*(double)j/128.0;
    t.c[j] = (float)ccos_d(a);
    t.s[j] = (float)csin_d(a);
  }
  return t;
}
constexpr TWT TW = make_tw();

// ---------- matched filter: out[row, l] = sum_k x[row, l+k-64] * conj(kernel[k]) ----------
// LDS-staged row (coalesced float4 HBM reads) + 32-slot register ring window,
// 8 consecutive outputs per thread. Half-row (2048 outputs) per 256-thread block.
__global__ __launch_bounds__(256, 4) void mf_kernel(const float* __restrict__ xr,
                                                    const float* __restrict__ xi,
                                                    const float* __restrict__ kr,
                                                    const float* __restrict__ ki,
                                                    float2* __restrict__ out)
{
  const int row = blockIdx.x >> 1;        // b*S + s
  const int l0  = (blockIdx.x & 1) * 2048;
  const int t   = threadIdx.x;            // 256
  __shared__ float2 xs[2176];             // xs[i] = x[l0 + i - 64]
  __shared__ float2 ks[132];
  if (t < KK) ks[t] = make_float2(kr[t], ki[t]);

  const float* xrr = xr + (size_t)row*LL;
  const float* xir = xi + (size_t)row*LL;
  for (int i4 = t; i4 < 544; i4 += 256){  // 544 groups of 4 float2
    const int g0 = l0 - 64 + i4*4;        // first float index
    float4 a, c;
    if (g0 >= 0 && g0 + 3 < LL){
      a = *(const float4*)(xrr + g0);
      c = *(const float4*)(xir + g0);
    } else {
      float av[4], cv[4];
      #pragma unroll
      for (int e = 0; e < 4; ++e){
        const int g = g0 + e;
        const bool ok = (g >= 0 && g < LL);
        av[e] = ok ? xrr[g] : 0.0f;
        cv[e] = ok ? xir[g] : 0.0f;
      }
      a = make_float4(av[0],av[1],av[2],av[3]);
      c = make_float4(cv[0],cv[1],cv[2],cv[3]);
    }
    const int i = i4*4;
    xs[i]   = make_float2(a.x, c.x);
    xs[i+1] = make_float2(a.y, c.y);
    xs[i+2] = make_float2(a.z, c.z);
    xs[i+3] = make_float2(a.w, c.w);
  }
  __syncthreads();

  const int base_l = t*8;                 // LDS fl2 index of v=0
  // ring: slot (v&31) holds x[l0 + t*8 + v - 64] = xs[base_l + v]
  float wr_[32], wi_[32];
  #pragma unroll
  for (int v = 0; v < 24; v += 2){
    const float4 p = *(const float4*)(&xs[base_l + v]);
    wr_[v]   = p.x; wi_[v]   = p.y;
    wr_[v+1] = p.z; wi_[v+1] = p.w;
  }

  float2 acc[8];
  #pragma unroll
  for (int j = 0; j < 8; j++) acc[j] = make_float2(0.0f, 0.0f);

  // 16 chunks of 8 taps; chunk q reads v in [q*8, q*8+15); refill fills [q*8+24, q*8+32)
  #pragma unroll 1
  for (int q4 = 0; q4 < 4; ++q4){
    #pragma unroll
    for (int qq = 0; qq < 4; ++qq){
      const int q = q4*4 + qq;
      float2 wv[8];
      #pragma unroll
      for (int kk = 0; kk < 8; ++kk) wv[kk] = ks[q*8 + kk];   // uniform -> broadcast
      #pragma unroll
      for (int kk = 0; kk < 8; ++kk){
        const float wx = wv[kk].x, wy = wv[kk].y;
        #pragma unroll
        for (int j = 0; j < 8; ++j){
          const int sl = (qq*8 + kk + j) & 31;   // == (q*8+kk+j)&31
          const float xvr = wr_[sl], xvi = wi_[sl];
          acc[j].x = fmaf(xvr, wx, acc[j].x);
          acc[j].x = fmaf(xvi, wy, acc[j].x);
          acc[j].y = fmaf(xvi, wx, acc[j].y);
          acc[j].y = fmaf(-xvr, wy, acc[j].y);
        }
      }
      if (q < 14){
        const int s0 = (qq*8 + 24) & 31;         // 24, 0, 8, 16
        const int vb = q*8 + 24;
        #pragma unroll
        for (int e = 0; e < 8; e += 2){
          const float4 p = *(const float4*)(&xs[base_l + vb + e]);
          wr_[s0+e]   = p.x; wi_[s0+e]   = p.y;
          wr_[s0+e+1] = p.z; wi_[s0+e+1] = p.w;
        }
      }
    }
  }
  { // tap k = 128: v = 128+j -> slot j
    const float2 w = ks[128];
    #pragma unroll
    for (int j = 0; j < 8; ++j){
      const float xvr = wr_[j], xvi = wi_[j];
      acc[j].x = fmaf(xvr, w.x, acc[j].x);
      acc[j].x = fmaf(xvi, w.y, acc[j].x);
      acc[j].y = fmaf(xvi, w.x, acc[j].y);
      acc[j].y = fmaf(-xvr, w.y, acc[j].y);
    }
  }

  float4* orow = (float4*)(out + (size_t)row*LL + l0 + base_l);
  #pragma unroll
  for (int q = 0; q < 4; ++q){
    orow[q] = make_float4(acc[2*q].x, acc[2*q].y, acc[2*q+1].x, acc[2*q+1].y);
  }
}

// ---------- init ----------
__global__ void init_kernel(const float* __restrict__ wpi,
                            float* __restrict__ w_mag, float* __restrict__ w_phase,
                            float2* __restrict__ cvec, unsigned long long* __restrict__ slots,
                            float* __restrict__ out)
{
  const int i = blockIdx.x*256 + threadIdx.x;
  if (i < BB*SS){
    float wp = wpi[i];
    w_mag[i] = 1.0f;
    w_phase[i] = wp;
    float phi = atanf(wp);
    float s, c;
    sincosf(phi, &s, &c);
    cvec[i] = make_float2(c, -s);      // m = 1 exactly (softmax of equal values)
  }
  if (i < BB) slots[i] = 0ull;
  if (i == 0) out[0] = 0.0f;
}

// ---------- in-register FFT DIF stage over N points ----------
template<int SPAN, int N>
__device__ __forceinline__ void fstage(float2* v){
  #pragma unroll
  for (int b0 = 0; b0 < N; b0 += 2*SPAN){
    #pragma unroll
    for (int j = 0; j < SPAN; j++){
      const int i0 = b0 + j, i1 = b0 + j + SPAN;
      float ax = v[i0].x, ay = v[i0].y, bx = v[i1].x, by = v[i1].y;
      float sx = ax - bx, sy = ay - by;
      v[i0].x = ax + bx; v[i0].y = ay + by;
      const int tj = j * (64 / SPAN);   // W_{2*SPAN}^j = TW[tj]
      if (tj == 0){
        v[i1].x = sx; v[i1].y = sy;
      } else if (tj == 32){             // W = -i
        v[i1].x = sy; v[i1].y = -sx;
      } else {
        const float wr = TW.c[tj], wi = TW.s[tj];
        v[i1].x = sx*wr - sy*wi;
        v[i1].y = sy*wr + sx*wi;
      }
    }
  }
}

// ---------- scan: per (b,l) compute max_k |FFT_128(c .* x[:,l])[k]|^2, argmax over l per b ----------
// 512 threads, 128 l per block. Slab [64 s][pitch 130] loaded in two s-halves
// (one 66KB buffer reused) with full-1KB-row coalesced global reads; bank-minimal
// LDS pattern. FFT math identical to the validated round-2/3 kernel.
__global__ __launch_bounds__(512, 4) void scan_kernel(const float2* __restrict__ xmf,
                                                      const float2* __restrict__ cvec,
                                                      unsigned long long* __restrict__ slots)
{
  const int b = blockIdx.y;
  const int tid = threadIdx.x;
  const int l0 = blockIdx.x * 128;
  __shared__ float2 csh[SS];
  __shared__ float2 xsh[64][130];        // 66,560 B; pitch 130 keeps float4 stores aligned
  __shared__ unsigned long long wred[8];
  if (tid < SS) csh[tid] = cvec[b*SS + tid];

  const int f = tid >> 2, r = tid & 3;   // 4 lanes per FFT; l = l0 + f
  float2 v[32];

  #pragma unroll 1
  for (int h = 0; h < 2; ++h){
    __syncthreads();                     // h=1: wait until half-0 consumers done
    const float2* src = xmf + ((size_t)(b*SS + h*64))*LL + l0;
    #pragma unroll
    for (int it = 0; it < 8; ++it){
      const int flat = it*512 + tid;     // one full 1KB row per wave-instruction
      const int s1 = flat >> 6;
      const int c4 = flat & 63;
      const float4 vv = *(const float4*)(src + (size_t)s1*LL + c4*2);
      *(float4*)(&xsh[s1][c4*2]) = vv;
    }
    __syncthreads();
    if ((r >> 1) == h){                  // lanes whose s-range lives in this half
      #pragma unroll
      for (int j = 0; j < 32; ++j){
        const int rowi = (r & 1)*32 + j;
        const float2 x = xsh[rowi][f];
        const float2 c = csh[r*32 + j];
        v[j].x = c.x*x.x - c.y*x.y;
        v[j].y = c.x*x.y + c.y*x.x;
      }
    }
  }

  // stage 1 (span 64): partner = tid^2.  r<2 keep sum; r>=2 hold (p - v)*W128^{(r-2)*32+j}
  {
    const bool hi = (r & 2) != 0;
    const float sgn = hi ? -1.0f : 1.0f;
    const bool odd = (r & 1) != 0;
    #pragma unroll
    for (int j = 0; j < 32; ++j){
      float px = __shfl_xor(v[j].x, 2);
      float py = __shfl_xor(v[j].y, 2);
      float ux = fmaf(sgn, v[j].x, px);
      float uy = fmaf(sgn, v[j].y, py);
      float wr = hi ? (odd ? TW.s[j] : TW.c[j]) : 1.0f;   // r=3: W128^{32+j} = (s, -c)
      float wi = hi ? (odd ? -TW.c[j] : TW.s[j]) : 0.0f;
      v[j].x = ux*wr - uy*wi;
      v[j].y = uy*wr + ux*wi;
    }
  }
  // stage 2 (span 32 within each 64-FFT): partner = tid^1
  {
    const bool hi = (r & 1) != 0;
    const float sgn = hi ? -1.0f : 1.0f;
    #pragma unroll
    for (int j = 0; j < 32; ++j){
      float px = __shfl_xor(v[j].x, 1);
      float py = __shfl_xor(v[j].y, 1);
      float ux = fmaf(sgn, v[j].x, px);
      float uy = fmaf(sgn, v[j].y, py);
      float wr = hi ? TW.c[2*j] : 1.0f;                   // W64^j = TW[2j]
      float wi = hi ? TW.s[2*j] : 0.0f;
      v[j].x = ux*wr - uy*wi;
      v[j].y = uy*wr + ux*wi;
    }
  }
  // local FFT-32 (bit-reversed bins; irrelevant for max)
  fstage<16,32>(v); fstage<8,32>(v); fstage<4,32>(v); fstage<2,32>(v); fstage<1,32>(v);

  float mm = 0.0f;
  #pragma unroll
  for (int j = 0; j < 32; ++j) mm = fmaxf(mm, v[j].x*v[j].x + v[j].y*v[j].y);
  mm = fmaxf(mm, __shfl_xor(mm, 1));
  mm = fmaxf(mm, __shfl_xor(mm, 2));     // per-FFT max on all 4 lanes

  unsigned long long pk = ((unsigned long long)__float_as_uint(mm) << 32) | (unsigned int)(l0 + f);
  #pragma unroll
  for (int m = 4; m < 64; m <<= 1){
    unsigned long long o = __shfl_xor(pk, m);
    if (o > pk) pk = o;
  }
  if ((tid & 63) == 0) wred[tid >> 6] = pk;
  __syncthreads();
  if (tid == 0){
    unsigned long long best = wred[0];
    #pragma unroll
    for (int w = 1; w < 8; ++w) if (wred[w] > best) best = wred[w];
    atomicMax(slots + b, best);
  }
}

// ---------- wave + block (256 thr / 4 waves) reductions ----------
__device__ __forceinline__ float wredsum(float v){
  #pragma unroll
  for (int m = 1; m < 64; m <<= 1) v += __shfl_xor(v, m);
  return v;
}
__device__ __forceinline__ float wredmax(float v){
  #pragma unroll
  for (int m = 1; m < 64; m <<= 1) v = fmaxf(v, __shfl_xor(v, m));
  return v;
}
__device__ __forceinline__ float bsum256(float v, float* red4, int t){
  v = wredsum(v);
  __syncthreads();                       // protect previous contents of red4
  if ((t & 63) == 0) red4[t >> 6] = v;
  __syncthreads();
  return red4[0] + red4[1] + red4[2] + red4[3];
}
__device__ __forceinline__ float bmax256(float v, float* red4, int t){
  v = wredmax(v);
  __syncthreads();
  if ((t & 63) == 0) red4[t >> 6] = v;
  __syncthreads();
  return fmaxf(fmaxf(red4[0], red4[1]), fmaxf(red4[2], red4[3]));
}

// ---------- per-step gradient + update (or final SNR); one block per b, 256 threads ----------
// thread t: s (or k) = t>>1, h = t&1 sums one half of each 128-term DFT; combine via shfl_xor(1).
__global__ __launch_bounds__(256) void step_kernel(const float2* __restrict__ xmf,
                                                   float* __restrict__ w_mag,
                                                   float* __restrict__ w_phase,
                                                   float2* __restrict__ cvec,
                                                   unsigned long long* __restrict__ slots,
                                                   const float* __restrict__ lsm,
                                                   const float* __restrict__ lsp,
                                                   int stepi, int isFinal,
                                                   float* __restrict__ out)
{
  const int b = blockIdx.x, t = threadIdx.x;
  const int s = t >> 1, h = t & 1;
  __shared__ float2 ysh[SS];
  __shared__ float twc[SS], tws[SS];     // e^{-2 pi i j/128} = (twc, tws)
  __shared__ float red4[4];
  __shared__ float speak;
  __shared__ int sidx;

  const int rbin = (int)(slots[b] & 0xffffffffull);
  const float wm0 = w_mag[b*SS + s];
  const float wp0 = w_phase[b*SS + s];
  const float2 xc = xmf[((size_t)(b*SS + s))*LL + rbin];
  float phi = atanf(wp0);
  float sph, cph;
  sincosf(phi, &sph, &cph);
  {
    int id = t & 127;
    float sv, cv;
    sincosf((float)(2.0*PI_D/128.0) * (float)id, &sv, &cv);
    twc[id] = cv; tws[id] = -sv;
  }
  // softmax -> m = S * softmax(w_mag)   (each s appears twice; sums scaled by 0.5)
  float mx = bmax256(wm0, red4, t);
  float ex = expf(wm0 - mx);
  float sm = bsum256(ex, red4, t) * 0.5f;
  float m = 128.0f * ex / sm;
  float cre = m*cph, cim = -m*sph;
  ysh[s] = make_float2(cre*xc.x - cim*xc.y, cre*xc.y + cim*xc.x);
  __syncthreads();

  // F[k] = sum_s e^{-2 pi i k s/128} y[s];  k = t>>1, halves combined via shfl
  const int k = s;
  float Fr = 0.0f, Fi = 0.0f;
  #pragma unroll 8
  for (int q = 0; q < 64; ++q){
    int s2 = h*64 + q;
    int id = (k*s2) & 127;
    float wr = twc[id], wi = tws[id];
    float2 ys = ysh[s2];
    Fr += wr*ys.x - wi*ys.y;
    Fi += wr*ys.y + wi*ys.x;
  }
  Fr += __shfl_xor(Fr, 1);
  Fi += __shfl_xor(Fi, 1);
  const int u = (k + 64) & 127;          // fftshifted index this pair owns
  float colu = Fr*Fr + Fi*Fi;

  float total = bsum256(colu, red4, t) * 0.5f;
  float zre = bsum256(colu * twc[u], red4, t) * 0.5f;    // e^{+i*2pi*u/128} = (twc[u], -tws[u])
  float zim = bsum256(colu * (-tws[u]), red4, t) * 0.5f;
  if (t == 0){
    float ang = atan2f(zim, zre);
    float pidx = ang * (128.0f/(2.0f*(float)PI_D));
    sidx = ((int)rintf(pidx)) & 127;     // round half-even == jnp.round; &127 == mod 128
  }
  __syncthreads();
  const int idx = sidx;
  if (u == idx && h == 0) speak = colu;
  __syncthreads();
  const float peak = speak;
  const float noise = (total - peak) * (1.0f/127.0f);

  if (isFinal){
    if (t == 0) atomicAdd(out, 10.0f*(log10f(peak) - log10f(noise)) * (1.0f/(float)BB));
    return;
  }

  constexpr float C10 = 4.342944819032518f;   // 10/ln(10)
  float g = (u == idx) ? (C10/peak) : (-C10/(127.0f*noise));
  __syncthreads();                        // all reads of y done
  ysh[k] = make_float2(2.0f*g*Fr, 2.0f*g*Fi);  // G[k]; both h write identical value
  __syncthreads();

  // T[s] = sum_k e^{+2 pi i k s/128} G[k]
  float Tr = 0.0f, Ti = 0.0f;
  #pragma unroll 8
  for (int q = 0; q < 64; ++q){
    int kk = h*64 + q;
    int id = (s*kk) & 127;
    float wr = twc[id], wi = -tws[id];
    float2 G = ysh[kk];
    Tr += wr*G.x - wi*G.y;
    Ti += wr*G.y + wi*G.x;
  }
  Tr += __shfl_xor(Tr, 1);
  Ti += __shfl_xor(Ti, 1);

  // H = conj(x_col) * T
  float Hr = xc.x*Tr + xc.y*Ti;
  float Hi = xc.x*Ti - xc.y*Tr;
  float dm   = Hr*cph - Hi*sph;                 // dL/dm
  float dphi = -m*(Hr*sph + Hi*cph);            // dL/dphi
  float S1 = bsum256(m*dm, red4, t) * 0.5f;
  float gwm = m*(dm - S1*(1.0f/128.0f));
  float gwp = dphi / (1.0f + wp0*wp0);

  constexpr float LN10 = 2.302585092994046f;
  float lrm = expf(lsm[s*NST + stepi] * LN10);
  float lrp = expf(lsp[s*NST + stepi] * LN10);
  float wm1 = wm0 + lrm*gwm;
  float wp1 = wp0 + lrp*gwp;
  if (h == 0){
    w_mag[b*SS + s] = wm1;
    w_phase[b*SS + s] = wp1;
  }

  // c for the next scan
  float mx2 = bmax256(wm1, red4, t);
  float ex2 = expf(wm1 - mx2);
  float sm2 = bsum256(ex2, red4, t) * 0.5f;
  float m2 = 128.0f * ex2 / sm2;
  float phi2 = atanf(wp1);
  float s2v, c2v;
  sincosf(phi2, &s2v, &c2v);
  if (h == 0) cvec[b*SS + s] = make_float2(m2*c2v, -m2*s2v);
  if (t == 0) slots[b] = 0ull;                  // reset argmax slot for next scan
}

extern "C" void kernel_launch(void* const* d_in, const int* in_sizes, int n_in,
                              void* d_out, int out_size, void* d_ws, size_t ws_size,
                              hipStream_t stream)
{
  const float* x_re = (const float*)d_in[0];
  const float* x_im = (const float*)d_in[1];
  const float* k_re = (const float*)d_in[2];
  const float* k_im = (const float*)d_in[3];
  const float* lsm  = (const float*)d_in[4];
  const float* lsp  = (const float*)d_in[5];
  const float* wpi  = (const float*)d_in[6];
  float* out = (float*)d_out;

  char* ws = (char*)d_ws;
  size_t off = 0;
  float2* xmf = (float2*)(ws + off);                 off += (size_t)BB*SS*LL*sizeof(float2);
  unsigned long long* slots = (unsigned long long*)(ws + off); off += 256;
  float* w_mag   = (float*)(ws + off);               off += (size_t)BB*SS*4;
  float* w_phase = (float*)(ws + off);               off += (size_t)BB*SS*4;
  float2* cvec   = (float2*)(ws + off);              off += (size_t)BB*SS*8;
  if (ws_size < off) return;   // insufficient scratch -> fail visibly

  mf_kernel<<<BB*SS*2, 256, 0, stream>>>(x_re, x_im, k_re, k_im, xmf);
  init_kernel<<<(BB*SS + 255)/256, 256, 0, stream>>>(wpi, w_mag, w_phase, cvec, slots, out);
  for (int i = 0; i < NST; i++){
    scan_kernel<<<dim3(LL/128, BB), 512, 0, stream>>>(xmf, cvec, slots);
    step_kernel<<<BB, 256, 0, stream>>>(xmf, w_mag, w_phase, cvec, slots, lsm, lsp, i, 0, out);
  }
  scan_kernel<<<dim3(LL/128, BB), 512, 0, stream>>>(xmf, cvec, slots);
  step_kernel<<<BB, 256, 0, stream>>>(xmf, w_mag, w_phase, cvec, slots, lsm, lsp, 0, 1, out);
}

// Round 5
// 789.071 us; speedup vs baseline: 2.3890x; 2.3890x over previous
//
#include <hip/hip_runtime.h>

#define BB 32
#define SS 128
#define LL 4096
#define KK 129
#define NST 10

// ---------- constexpr twiddles: TW[j] = e^{-2*pi*i*j/128}, j in [0,64) ----------
constexpr double PI_D = 3.141592653589793238462643383279502884;
constexpr double red_sin(double x){ // |x| <= pi/2, Taylor to x^17
  double x2 = x*x, t = x, r = x;
  t *= -x2/6.0;   r += t;
  t *= -x2/20.0;  r += t;
  t *= -x2/42.0;  r += t;
  t *= -x2/72.0;  r += t;
  t *= -x2/110.0; r += t;
  t *= -x2/156.0; r += t;
  t *= -x2/210.0; r += t;
  t *= -x2/272.0; r += t;
  return r;
}
constexpr double csin_d(double x){
  while (x >  PI_D) x -= 2.0*PI_D;
  while (x < -PI_D) x += 2.0*PI_D;
  if (x >  PI_D*0.5)      x =  PI_D - x;
  else if (x < -PI_D*0.5) x = -PI_D - x;
  return red_sin(x);
}
constexpr double ccos_d(double x){ return csin_d(x + PI_D*0.5); }
struct TWT { float c[64]; float s[64]; };
constexpr TWT make_tw(){
  TWT t{};
  for (int j = 0; j < 64; j++){
    double a = -2.0*PI_D*(double)j/128.0;
    t.c[j] = (float)ccos_d(a);
    t.s[j] = (float)csin_d(a);
  }
  return t;
}
constexpr TWT TW = make_tw();

// LDS pad: +1 float2 per 8 -> lane-bank map 18t mod 32 (all 16 even residues, 4-way worst)
#define PHYS8(i) ((i) + ((i) >> 3))

// ---------- matched filter: out[row, l] = sum_k x[row, l+k-64] * conj(kernel[k]) ----------
// LDS-staged half-row + 16-slot register ring (4-tap chunks), 8 outputs/thread.
// No min-waves launch bound (r4's 4-waves bound forced a full ring spill: 4.4GB scratch writes).
__global__ __launch_bounds__(256) void mf_kernel(const float* __restrict__ xr,
                                                 const float* __restrict__ xi,
                                                 const float* __restrict__ kr,
                                                 const float* __restrict__ ki,
                                                 float2* __restrict__ out)
{
  const int row = blockIdx.x >> 1;        // b*S + s
  const int l0  = (blockIdx.x & 1) * 2048;
  const int t   = threadIdx.x;            // 256
  __shared__ float2 xs[2456];             // PHYS8(2175)=2446; xs[PHYS8(i)] = x[l0 + i - 64]
  __shared__ float2 ks[132];
  if (t < KK) ks[t] = make_float2(kr[t], ki[t]);

  const float* xrr = xr + (size_t)row*LL;
  const float* xir = xi + (size_t)row*LL;
  for (int i4 = t; i4 < 544; i4 += 256){  // 544 groups of 4 float2
    const int g0 = l0 - 64 + i4*4;        // first float index
    float4 a, c;
    if (g0 >= 0 && g0 + 3 < LL){
      a = *(const float4*)(xrr + g0);
      c = *(const float4*)(xir + g0);
    } else {
      float av[4], cv[4];
      #pragma unroll
      for (int e = 0; e < 4; ++e){
        const int g = g0 + e;
        const bool ok = (g >= 0 && g < LL);
        av[e] = ok ? xrr[g] : 0.0f;
        cv[e] = ok ? xir[g] : 0.0f;
      }
      a = make_float4(av[0],av[1],av[2],av[3]);
      c = make_float4(cv[0],cv[1],cv[2],cv[3]);
    }
    const int i = i4*4;                   // i%8 in {0,4}: all 4 fl2 contiguous after PHYS8
    const int p = PHYS8(i);
    xs[p]   = make_float2(a.x, c.x);
    xs[p+1] = make_float2(a.y, c.y);
    xs[p+2] = make_float2(a.z, c.z);
    xs[p+3] = make_float2(a.w, c.w);
  }
  __syncthreads();

  const int base_l = t*8;                 // logical fl2 index of v=0
  // ring: slot (v&15) holds xs-logical[base_l + v]
  float wr_[16], wi_[16];
  #pragma unroll
  for (int v = 0; v < 12; v += 2){        // preload v in [0,12)
    const float4 p = *(const float4*)(&xs[PHYS8(base_l + v)]);
    wr_[v]   = p.x; wi_[v]   = p.y;
    wr_[v+1] = p.z; wi_[v+1] = p.w;
  }

  float2 acc[8];
  #pragma unroll
  for (int j = 0; j < 8; j++) acc[j] = make_float2(0.0f, 0.0f);

  // 32 chunks of 4 taps; chunk q reads v in [q*4, q*4+11], refill fills [q*4+12, q*4+16)
  #pragma unroll 1
  for (int q8 = 0; q8 < 8; ++q8){
    #pragma unroll
    for (int qq = 0; qq < 4; ++qq){
      const int q = q8*4 + qq;
      // issue refill early (landing slots disjoint from live range; commit after FMAs)
      float4 p0, p1;
      const bool doref = (q < 31);
      if (doref){
        const int v0 = base_l + q*4 + 12;
        p0 = *(const float4*)(&xs[PHYS8(v0)]);
        p1 = *(const float4*)(&xs[PHYS8(v0 + 2)]);
      }
      float2 wv[4];
      #pragma unroll
      for (int kk = 0; kk < 4; ++kk) wv[kk] = ks[q*4 + kk];   // uniform -> broadcast
      #pragma unroll
      for (int kk = 0; kk < 4; ++kk){
        const float wx = wv[kk].x, wy = wv[kk].y;
        #pragma unroll
        for (int j = 0; j < 8; ++j){
          const int sl = (qq*4 + kk + j) & 15;   // == (q*4+kk+j)&15
          const float xvr = wr_[sl], xvi = wi_[sl];
          acc[j].x = fmaf(xvr, wx, acc[j].x);
          acc[j].x = fmaf(xvi, wy, acc[j].x);
          acc[j].y = fmaf(xvi, wx, acc[j].y);
          acc[j].y = fmaf(-xvr, wy, acc[j].y);
        }
      }
      if (doref){
        const int s0 = (qq*4 + 12) & 15;         // 12, 0, 4, 8
        wr_[s0]   = p0.x; wi_[s0]   = p0.y;
        wr_[s0+1] = p0.z; wi_[s0+1] = p0.w;
        wr_[s0+2] = p1.x; wi_[s0+2] = p1.y;
        wr_[s0+3] = p1.z; wi_[s0+3] = p1.w;
      }
    }
  }
  { // tap k = 128: v = 128+j -> slot j
    const float2 w = ks[128];
    #pragma unroll
    for (int j = 0; j < 8; ++j){
      const float xvr = wr_[j], xvi = wi_[j];
      acc[j].x = fmaf(xvr, w.x, acc[j].x);
      acc[j].x = fmaf(xvi, w.y, acc[j].x);
      acc[j].y = fmaf(xvi, w.x, acc[j].y);
      acc[j].y = fmaf(-xvr, w.y, acc[j].y);
    }
  }

  float4* orow = (float4*)(out + (size_t)row*LL + l0 + base_l);
  #pragma unroll
  for (int q = 0; q < 4; ++q){
    orow[q] = make_float4(acc[2*q].x, acc[2*q].y, acc[2*q+1].x, acc[2*q+1].y);
  }
}

// ---------- init ----------
__global__ void init_kernel(const float* __restrict__ wpi,
                            float* __restrict__ w_mag, float* __restrict__ w_phase,
                            float2* __restrict__ cvec, unsigned long long* __restrict__ slots,
                            float* __restrict__ out)
{
  const int i = blockIdx.x*256 + threadIdx.x;
  if (i < BB*SS){
    float wp = wpi[i];
    w_mag[i] = 1.0f;
    w_phase[i] = wp;
    float phi = atanf(wp);
    float s, c;
    sincosf(phi, &s, &c);
    cvec[i] = make_float2(c, -s);      // m = 1 exactly (softmax of equal values)
  }
  if (i < BB) slots[i] = 0ull;
  if (i == 0) out[0] = 0.0f;
}

// ---------- in-register FFT DIF stage over N points ----------
template<int SPAN, int N>
__device__ __forceinline__ void fstage(float2* v){
  #pragma unroll
  for (int b0 = 0; b0 < N; b0 += 2*SPAN){
    #pragma unroll
    for (int j = 0; j < SPAN; j++){
      const int i0 = b0 + j, i1 = b0 + j + SPAN;
      float ax = v[i0].x, ay = v[i0].y, bx = v[i1].x, by = v[i1].y;
      float sx = ax - bx, sy = ay - by;
      v[i0].x = ax + bx; v[i0].y = ay + by;
      const int tj = j * (64 / SPAN);   // W_{2*SPAN}^j = TW[tj]
      if (tj == 0){
        v[i1].x = sx; v[i1].y = sy;
      } else if (tj == 32){             // W = -i
        v[i1].x = sy; v[i1].y = -sx;
      } else {
        const float wr = TW.c[tj], wi = TW.s[tj];
        v[i1].x = sx*wr - sy*wi;
        v[i1].y = sy*wr + sx*wi;
      }
    }
  }
}

// ---------- scan: per (b,l) compute max_k |FFT_128(c .* x[:,l])[k]|^2, argmax over l per b ----------
// 512 threads, 128 l per block. Slab [64 s][pitch 130] loaded in two s-halves
// (one 66KB buffer reused) with full-1KB-row coalesced global reads.
__global__ __launch_bounds__(512, 4) void scan_kernel(const float2* __restrict__ xmf,
                                                      const float2* __restrict__ cvec,
                                                      unsigned long long* __restrict__ slots)
{
  const int b = blockIdx.y;
  const int tid = threadIdx.x;
  const int l0 = blockIdx.x * 128;
  __shared__ float2 csh[SS];
  __shared__ float2 xsh[64][130];        // 66,560 B; pitch 130 keeps float4 stores aligned
  __shared__ unsigned long long wred[8];
  if (tid < SS) csh[tid] = cvec[b*SS + tid];

  const int f = tid >> 2, r = tid & 3;   // 4 lanes per FFT; l = l0 + f
  float2 v[32];

  #pragma unroll 1
  for (int h = 0; h < 2; ++h){
    __syncthreads();                     // h=1: wait until half-0 consumers done
    const float2* src = xmf + ((size_t)(b*SS + h*64))*LL + l0;
    #pragma unroll
    for (int it = 0; it < 8; ++it){
      const int flat = it*512 + tid;     // one full 1KB row per wave-instruction
      const int s1 = flat >> 6;
      const int c4 = flat & 63;
      const float4 vv = *(const float4*)(src + (size_t)s1*LL + c4*2);
      *(float4*)(&xsh[s1][c4*2]) = vv;
    }
    __syncthreads();
    if ((r >> 1) == h){                  // lanes whose s-range lives in this half
      #pragma unroll
      for (int j = 0; j < 32; ++j){
        const int rowi = (r & 1)*32 + j;
        const float2 x = xsh[rowi][f];
        const float2 c = csh[r*32 + j];
        v[j].x = c.x*x.x - c.y*x.y;
        v[j].y = c.x*x.y + c.y*x.x;
      }
    }
  }

  // stage 1 (span 64): partner = tid^2.  r<2 keep sum; r>=2 hold (p - v)*W128^{(r-2)*32+j}
  {
    const bool hi = (r & 2) != 0;
    const float sgn = hi ? -1.0f : 1.0f;
    const bool odd = (r & 1) != 0;
    #pragma unroll
    for (int j = 0; j < 32; ++j){
      float px = __shfl_xor(v[j].x, 2);
      float py = __shfl_xor(v[j].y, 2);
      float ux = fmaf(sgn, v[j].x, px);
      float uy = fmaf(sgn, v[j].y, py);
      float wr = hi ? (odd ? TW.s[j] : TW.c[j]) : 1.0f;   // r=3: W128^{32+j} = (s, -c)
      float wi = hi ? (odd ? -TW.c[j] : TW.s[j]) : 0.0f;
      v[j].x = ux*wr - uy*wi;
      v[j].y = uy*wr + ux*wi;
    }
  }
  // stage 2 (span 32 within each 64-FFT): partner = tid^1
  {
    const bool hi = (r & 1) != 0;
    const float sgn = hi ? -1.0f : 1.0f;
    #pragma unroll
    for (int j = 0; j < 32; ++j){
      float px = __shfl_xor(v[j].x, 1);
      float py = __shfl_xor(v[j].y, 1);
      float ux = fmaf(sgn, v[j].x, px);
      float uy = fmaf(sgn, v[j].y, py);
      float wr = hi ? TW.c[2*j] : 1.0f;                   // W64^j = TW[2j]
      float wi = hi ? TW.s[2*j] : 0.0f;
      v[j].x = ux*wr - uy*wi;
      v[j].y = uy*wr + ux*wi;
    }
  }
  // local FFT-32 (bit-reversed bins; irrelevant for max)
  fstage<16,32>(v); fstage<8,32>(v); fstage<4,32>(v); fstage<2,32>(v); fstage<1,32>(v);

  float mm = 0.0f;
  #pragma unroll
  for (int j = 0; j < 32; ++j) mm = fmaxf(mm, v[j].x*v[j].x + v[j].y*v[j].y);
  mm = fmaxf(mm, __shfl_xor(mm, 1));
  mm = fmaxf(mm, __shfl_xor(mm, 2));     // per-FFT max on all 4 lanes

  unsigned long long pk = ((unsigned long long)__float_as_uint(mm) << 32) | (unsigned int)(l0 + f);
  #pragma unroll
  for (int m = 4; m < 64; m <<= 1){
    unsigned long long o = __shfl_xor(pk, m);
    if (o > pk) pk = o;
  }
  if ((tid & 63) == 0) wred[tid >> 6] = pk;
  __syncthreads();
  if (tid == 0){
    unsigned long long best = wred[0];
    #pragma unroll
    for (int w = 1; w < 8; ++w) if (wred[w] > best) best = wred[w];
    atomicMax(slots + b, best);
  }
}

// ---------- wave + block (256 thr / 4 waves) reductions ----------
__device__ __forceinline__ float wredsum(float v){
  #pragma unroll
  for (int m = 1; m < 64; m <<= 1) v += __shfl_xor(v, m);
  return v;
}
__device__ __forceinline__ float wredmax(float v){
  #pragma unroll
  for (int m = 1; m < 64; m <<= 1) v = fmaxf(v, __shfl_xor(v, m));
  return v;
}
__device__ __forceinline__ float bsum256(float v, float* red4, int t){
  v = wredsum(v);
  __syncthreads();                       // protect previous contents of red4
  if ((t & 63) == 0) red4[t >> 6] = v;
  __syncthreads();
  return red4[0] + red4[1] + red4[2] + red4[3];
}
__device__ __forceinline__ float bmax256(float v, float* red4, int t){
  v = wredmax(v);
  __syncthreads();
  if ((t & 63) == 0) red4[t >> 6] = v;
  __syncthreads();
  return fmaxf(fmaxf(red4[0], red4[1]), fmaxf(red4[2], red4[3]));
}

// ---------- per-step gradient + update (or final SNR); one block per b, 256 threads ----------
// thread t: s (or k) = t>>1, h = t&1 sums one half of each 128-term DFT; combine via shfl_xor(1).
__global__ __launch_bounds__(256) void step_kernel(const float2* __restrict__ xmf,
                                                   float* __restrict__ w_mag,
                                                   float* __restrict__ w_phase,
                                                   float2* __restrict__ cvec,
                                                   unsigned long long* __restrict__ slots,
                                                   const float* __restrict__ lsm,
                                                   const float* __restrict__ lsp,
                                                   int stepi, int isFinal,
                                                   float* __restrict__ out)
{
  const int b = blockIdx.x, t = threadIdx.x;
  const int s = t >> 1, h = t & 1;
  __shared__ float2 ysh[SS];
  __shared__ float twc[SS], tws[SS];     // e^{-2 pi i j/128} = (twc, tws)
  __shared__ float red4[4];
  __shared__ float speak;
  __shared__ int sidx;

  const int rbin = (int)(slots[b] & 0xffffffffull);
  const float wm0 = w_mag[b*SS + s];
  const float wp0 = w_phase[b*SS + s];
  const float2 xc = xmf[((size_t)(b*SS + s))*LL + rbin];
  float phi = atanf(wp0);
  float sph, cph;
  sincosf(phi, &sph, &cph);
  {
    int id = t & 127;
    float sv, cv;
    sincosf((float)(2.0*PI_D/128.0) * (float)id, &sv, &cv);
    twc[id] = cv; tws[id] = -sv;
  }
  // softmax -> m = S * softmax(w_mag)   (each s appears twice; sums scaled by 0.5)
  float mx = bmax256(wm0, red4, t);
  float ex = expf(wm0 - mx);
  float sm = bsum256(ex, red4, t) * 0.5f;
  float m = 128.0f * ex / sm;
  float cre = m*cph, cim = -m*sph;
  ysh[s] = make_float2(cre*xc.x - cim*xc.y, cre*xc.y + cim*xc.x);
  __syncthreads();

  // F[k] = sum_s e^{-2 pi i k s/128} y[s];  k = t>>1, halves combined via shfl
  const int k = s;
  float Fr = 0.0f, Fi = 0.0f;
  #pragma unroll 8
  for (int q = 0; q < 64; ++q){
    int s2 = h*64 + q;
    int id = (k*s2) & 127;
    float wr = twc[id], wi = tws[id];
    float2 ys = ysh[s2];
    Fr += wr*ys.x - wi*ys.y;
    Fi += wr*ys.y + wi*ys.x;
  }
  Fr += __shfl_xor(Fr, 1);
  Fi += __shfl_xor(Fi, 1);
  const int u = (k + 64) & 127;          // fftshifted index this pair owns
  float colu = Fr*Fr + Fi*Fi;

  float total = bsum256(colu, red4, t) * 0.5f;
  float zre = bsum256(colu * twc[u], red4, t) * 0.5f;    // e^{+i*2pi*u/128} = (twc[u], -tws[u])
  float zim = bsum256(colu * (-tws[u]), red4, t) * 0.5f;
  if (t == 0){
    float ang = atan2f(zim, zre);
    float pidx = ang * (128.0f/(2.0f*(float)PI_D));
    sidx = ((int)rintf(pidx)) & 127;     // round half-even == jnp.round; &127 == mod 128
  }
  __syncthreads();
  const int idx = sidx;
  if (u == idx && h == 0) speak = colu;
  __syncthreads();
  const float peak = speak;
  const float noise = (total - peak) * (1.0f/127.0f);

  if (isFinal){
    if (t == 0) atomicAdd(out, 10.0f*(log10f(peak) - log10f(noise)) * (1.0f/(float)BB));
    return;
  }

  constexpr float C10 = 4.342944819032518f;   // 10/ln(10)
  float g = (u == idx) ? (C10/peak) : (-C10/(127.0f*noise));
  __syncthreads();                        // all reads of y done
  ysh[k] = make_float2(2.0f*g*Fr, 2.0f*g*Fi);  // G[k]; both h write identical value
  __syncthreads();

  // T[s] = sum_k e^{+2 pi i k s/128} G[k]
  float Tr = 0.0f, Ti = 0.0f;
  #pragma unroll 8
  for (int q = 0; q < 64; ++q){
    int kk = h*64 + q;
    int id = (s*kk) & 127;
    float wr = twc[id], wi = -tws[id];
    float2 G = ysh[kk];
    Tr += wr*G.x - wi*G.y;
    Ti += wr*G.y + wi*G.x;
  }
  Tr += __shfl_xor(Tr, 1);
  Ti += __shfl_xor(Ti, 1);

  // H = conj(x_col) * T
  float Hr = xc.x*Tr + xc.y*Ti;
  float Hi = xc.x*Ti - xc.y*Tr;
  float dm   = Hr*cph - Hi*sph;                 // dL/dm
  float dphi = -m*(Hr*sph + Hi*cph);            // dL/dphi
  float S1 = bsum256(m*dm, red4, t) * 0.5f;
  float gwm = m*(dm - S1*(1.0f/128.0f));
  float gwp = dphi / (1.0f + wp0*wp0);

  constexpr float LN10 = 2.302585092994046f;
  float lrm = expf(lsm[s*NST + stepi] * LN10);
  float lrp = expf(lsp[s*NST + stepi] * LN10);
  float wm1 = wm0 + lrm*gwm;
  float wp1 = wp0 + lrp*gwp;
  if (h == 0){
    w_mag[b*SS + s] = wm1;
    w_phase[b*SS + s] = wp1;
  }

  // c for the next scan
  float mx2 = bmax256(wm1, red4, t);
  float ex2 = expf(wm1 - mx2);
  float sm2 = bsum256(ex2, red4, t) * 0.5f;
  float m2 = 128.0f * ex2 / sm2;
  float phi2 = atanf(wp1);
  float s2v, c2v;
  sincosf(phi2, &s2v, &c2v);
  if (h == 0) cvec[b*SS + s] = make_float2(m2*c2v, -m2*s2v);
  if (t == 0) slots[b] = 0ull;                  // reset argmax slot for next scan
}

extern "C" void kernel_launch(void* const* d_in, const int* in_sizes, int n_in,
                              void* d_out, int out_size, void* d_ws, size_t ws_size,
                              hipStream_t stream)
{
  const float* x_re = (const float*)d_in[0];
  const float* x_im = (const float*)d_in[1];
  const float* k_re = (const float*)d_in[2];
  const float* k_im = (const float*)d_in[3];
  const float* lsm  = (const float*)d_in[4];
  const float* lsp  = (const float*)d_in[5];
  const float* wpi  = (const float*)d_in[6];
  float* out = (float*)d_out;

  char* ws = (char*)d_ws;
  size_t off = 0;
  float2* xmf = (float2*)(ws + off);                 off += (size_t)BB*SS*LL*sizeof(float2);
  unsigned long long* slots = (unsigned long long*)(ws + off); off += 256;
  float* w_mag   = (float*)(ws + off);               off += (size_t)BB*SS*4;
  float* w_phase = (float*)(ws + off);               off += (size_t)BB*SS*4;
  float2* cvec   = (float2*)(ws + off);              off += (size_t)BB*SS*8;
  if (ws_size < off) return;   // insufficient scratch -> fail visibly

  mf_kernel<<<BB*SS*2, 256, 0, stream>>>(x_re, x_im, k_re, k_im, xmf);
  init_kernel<<<(BB*SS + 255)/256, 256, 0, stream>>>(wpi, w_mag, w_phase, cvec, slots, out);
  for (int i = 0; i < NST; i++){
    scan_kernel<<<dim3(LL/128, BB), 512, 0, stream>>>(xmf, cvec, slots);
    step_kernel<<<BB, 256, 0, stream>>>(xmf, w_mag, w_phase, cvec, slots, lsm, lsp, i, 0, out);
  }
  scan_kernel<<<dim3(LL/128, BB), 512, 0, stream>>>(xmf, cvec, slots);
  step_kernel<<<BB, 256, 0, stream>>>(xmf, w_mag, w_phase, cvec, slots, lsm, lsp, 0, 1, out);
}